// Round 2
// baseline (1097.635 us; speedup 1.0000x reference)
//
#include <hip/hip_runtime.h>
#include <math.h>

#define B_   256
#define T_   1000
#define F_   310
#define H1   128
#define H2   64
#define MTOT (B_*T_)   // 256000

__device__ __forceinline__ float gelu_tanh(float x) {
  // flax/jax approximate gelu: 0.5*x*(1+tanh(sqrt(2/pi)*(x+0.044715*x^3)))
  float x3 = x*x*x;
  float t = tanhf(0.7978845608028654f * (x + 0.044715f * x3));
  return 0.5f * x * (1.0f + t);
}

// ---------------------------------------------------------------------------
// K1: x = LN(gelu(x_seq @ W1 + b1)); M=256000, K=310, N=128
// tile 128x128, BK=32, 256 threads, 8x8 per thread, LN fused in epilogue
// ---------------------------------------------------------------------------
__global__ __launch_bounds__(256) void k1_gemm_gelu_ln(
    const float* __restrict__ A, const float* __restrict__ W,
    const float* __restrict__ bias, const float* __restrict__ lns,
    const float* __restrict__ lnb, float* __restrict__ out)
{
  __shared__ float As[32][132];
  __shared__ float Bs[32][132];
  const int tid = threadIdx.x;
  const int ty = tid >> 4, tx = tid & 15;
  const int m0 = blockIdx.x * 128;

  float acc[8][8];
  #pragma unroll
  for (int i = 0; i < 8; ++i)
    #pragma unroll
    for (int j = 0; j < 8; ++j) acc[i][j] = 0.f;

  const int ar = tid >> 3;        // 0..31  (row within pass)
  const int ak = (tid & 7) * 4;   // 0..28  (k offset)
  const int br = tid >> 5;        // 0..7   (k row within pass)
  const int bc = (tid & 31) * 4;  // 0..124 (n offset)

  for (int kt = 0; kt < 10; ++kt) {
    const int k0 = kt * 32;
    // stage A tile (transposed into As[k][m])
    #pragma unroll
    for (int p = 0; p < 4; ++p) {
      const int r  = ar + p * 32;
      const int kk = k0 + ak;
      const float* src = A + (size_t)(m0 + r) * F_ + kk;
      float4 v;
      if (kk + 4 <= F_) {
        v = *(const float4*)src;
      } else {
        v.x = (kk + 0 < F_) ? src[0] : 0.f;
        v.y = (kk + 1 < F_) ? src[1] : 0.f;
        v.z = (kk + 2 < F_) ? src[2] : 0.f;
        v.w = (kk + 3 < F_) ? src[3] : 0.f;
      }
      As[ak + 0][r] = v.x; As[ak + 1][r] = v.y;
      As[ak + 2][r] = v.z; As[ak + 3][r] = v.w;
    }
    // stage B tile (W1 rows k0..k0+31, all 128 cols)
    #pragma unroll
    for (int p = 0; p < 4; ++p) {
      const int kk = k0 + br + p * 8;
      float4 v = make_float4(0.f, 0.f, 0.f, 0.f);
      if (kk < F_) v = *(const float4*)(W + (size_t)kk * H1 + bc);
      *(float4*)&Bs[br + p * 8][bc] = v;
    }
    __syncthreads();
    #pragma unroll
    for (int k = 0; k < 32; ++k) {
      float a[8], b[8];
      *(float4*)&a[0] = *(const float4*)&As[k][ty * 8];
      *(float4*)&a[4] = *(const float4*)&As[k][ty * 8 + 4];
      *(float4*)&b[0] = *(const float4*)&Bs[k][tx * 8];
      *(float4*)&b[4] = *(const float4*)&Bs[k][tx * 8 + 4];
      #pragma unroll
      for (int i = 0; i < 8; ++i)
        #pragma unroll
        for (int j = 0; j < 8; ++j) acc[i][j] = fmaf(a[i], b[j], acc[i][j]);
    }
    __syncthreads();
  }

  // epilogue: bias + gelu + LayerNorm over the 128 cols (16 tx threads/row)
  float bb[8], ss[8], sb[8];
  #pragma unroll
  for (int j = 0; j < 8; ++j) {
    bb[j] = bias[tx * 8 + j]; ss[j] = lns[tx * 8 + j]; sb[j] = lnb[tx * 8 + j];
  }
  #pragma unroll
  for (int i = 0; i < 8; ++i) {
    float g[8]; float sum = 0.f;
    #pragma unroll
    for (int j = 0; j < 8; ++j) { g[j] = gelu_tanh(acc[i][j] + bb[j]); sum += g[j]; }
    sum += __shfl_xor(sum, 1); sum += __shfl_xor(sum, 2);
    sum += __shfl_xor(sum, 4); sum += __shfl_xor(sum, 8);
    const float mu = sum * (1.0f / 128.0f);
    float vs = 0.f;
    #pragma unroll
    for (int j = 0; j < 8; ++j) { float dd = g[j] - mu; vs += dd * dd; }
    vs += __shfl_xor(vs, 1); vs += __shfl_xor(vs, 2);
    vs += __shfl_xor(vs, 4); vs += __shfl_xor(vs, 8);
    const float rstd = rsqrtf(vs * (1.0f / 128.0f) + 1e-6f);
    float o[8];
    #pragma unroll
    for (int j = 0; j < 8; ++j) o[j] = (g[j] - mu) * rstd * ss[j] + sb[j];
    float* dst = out + (size_t)(m0 + ty * 8 + i) * H1 + tx * 8;
    *(float4*)&dst[0] = *(float4*)&o[0];
    *(float4*)&dst[4] = *(float4*)&o[4];
  }
}

// ---------------------------------------------------------------------------
// K2: LIF scan over T, in place. One thread per (b,h). Chunked 8-deep
// double-buffered prefetch: 8 loads in flight while computing previous 8
// steps (recurrence chain only ~1-deep otherwise -> latency-bound).
// 64-thread blocks spread waves across all CUs.
// ---------------------------------------------------------------------------
__global__ __launch_bounds__(64) void k2_lif1(
    float* __restrict__ buf, const float* __restrict__ decay,
    unsigned int* __restrict__ cnt)
{
  const int gid = blockIdx.x * 64 + threadIdx.x;
  const int b = gid >> 7, h = gid & 127;
  const float d = 1.f / (1.f + expf(-decay[h]));
  float* p = buf + (size_t)b * T_ * H1 + h;
  float v = 0.f, z = 0.f;
  unsigned int c = 0;

  float xa[8], xb[8];
  #pragma unroll
  for (int j = 0; j < 8; ++j) xa[j] = p[(size_t)j * H1];

  for (int ch = 0; ch < 125; ++ch) {   // 125 * 8 = 1000
    const int tb = ch * 8;
    if (ch + 1 < 125) {
      #pragma unroll
      for (int j = 0; j < 8; ++j) xb[j] = p[(size_t)(tb + 8 + j) * H1];
    }
    #pragma unroll
    for (int j = 0; j < 8; ++j) {
      v = v * d * (1.f - z) + xa[j];
      const bool sp = (v - 0.5f > 0.f);
      z = sp ? 1.f : 0.f;
      c += sp;
      p[(size_t)(tb + j) * H1] = z;     // overwrites t<=tb+7; loads are >=tb+8
    }
    #pragma unroll
    for (int j = 0; j < 8; ++j) xa[j] = xb[j];
  }

  c += __shfl_xor(c, 1);  c += __shfl_xor(c, 2);  c += __shfl_xor(c, 4);
  c += __shfl_xor(c, 8);  c += __shfl_xor(c, 16); c += __shfl_xor(c, 32);
  if (threadIdx.x == 0) atomicAdd(cnt, c);
}

// ---------------------------------------------------------------------------
// K3: x2 = LN(spk1 @ W2 + b2); M=256000, K=128, N=64
// tile 128x64, BK=32, 256 threads, 8x4 per thread, LN fused
// ---------------------------------------------------------------------------
__global__ __launch_bounds__(256) void k3_gemm_ln(
    const float* __restrict__ A, const float* __restrict__ W,
    const float* __restrict__ bias, const float* __restrict__ lns,
    const float* __restrict__ lnb, float* __restrict__ out)
{
  __shared__ float As[32][132];
  __shared__ float Bs[32][68];
  const int tid = threadIdx.x;
  const int ty = tid >> 4, tx = tid & 15;
  const int m0 = blockIdx.x * 128;

  float acc[8][4];
  #pragma unroll
  for (int i = 0; i < 8; ++i)
    #pragma unroll
    for (int j = 0; j < 4; ++j) acc[i][j] = 0.f;

  const int ar = tid >> 3;        // 0..31
  const int ak = (tid & 7) * 4;   // 0..28
  const int br = tid >> 4;        // 0..15
  const int bc = (tid & 15) * 4;  // 0..60

  for (int kt = 0; kt < 4; ++kt) {
    const int k0 = kt * 32;
    #pragma unroll
    for (int p = 0; p < 4; ++p) {
      const int r = ar + p * 32;
      float4 v = *(const float4*)(A + (size_t)(m0 + r) * H1 + k0 + ak);
      As[ak + 0][r] = v.x; As[ak + 1][r] = v.y;
      As[ak + 2][r] = v.z; As[ak + 3][r] = v.w;
    }
    #pragma unroll
    for (int p = 0; p < 2; ++p) {
      const int kk = k0 + br + p * 16;
      *(float4*)&Bs[br + p * 16][bc] = *(const float4*)(W + (size_t)kk * H2 + bc);
    }
    __syncthreads();
    #pragma unroll
    for (int k = 0; k < 32; ++k) {
      float a[8], b[4];
      *(float4*)&a[0] = *(const float4*)&As[k][ty * 8];
      *(float4*)&a[4] = *(const float4*)&As[k][ty * 8 + 4];
      *(float4*)&b[0] = *(const float4*)&Bs[k][tx * 4];
      #pragma unroll
      for (int i = 0; i < 8; ++i)
        #pragma unroll
        for (int j = 0; j < 4; ++j) acc[i][j] = fmaf(a[i], b[j], acc[i][j]);
    }
    __syncthreads();
  }

  float bb[4], ss[4], sb[4];
  #pragma unroll
  for (int j = 0; j < 4; ++j) {
    bb[j] = bias[tx * 4 + j]; ss[j] = lns[tx * 4 + j]; sb[j] = lnb[tx * 4 + j];
  }
  #pragma unroll
  for (int i = 0; i < 8; ++i) {
    float g[4]; float sum = 0.f;
    #pragma unroll
    for (int j = 0; j < 4; ++j) { g[j] = acc[i][j] + bb[j]; sum += g[j]; }
    sum += __shfl_xor(sum, 1); sum += __shfl_xor(sum, 2);
    sum += __shfl_xor(sum, 4); sum += __shfl_xor(sum, 8);
    const float mu = sum * (1.0f / 64.0f);
    float vs = 0.f;
    #pragma unroll
    for (int j = 0; j < 4; ++j) { float dd = g[j] - mu; vs += dd * dd; }
    vs += __shfl_xor(vs, 1); vs += __shfl_xor(vs, 2);
    vs += __shfl_xor(vs, 4); vs += __shfl_xor(vs, 8);
    const float rstd = rsqrtf(vs * (1.0f / 64.0f) + 1e-6f);
    float o[4];
    #pragma unroll
    for (int j = 0; j < 4; ++j) o[j] = (g[j] - mu) * rstd * ss[j] + sb[j];
    float* dst = out + (size_t)(m0 + ty * 8 + i) * H2 + tx * 4;
    *(float4*)&dst[0] = *(float4*)&o[0];
  }
}

// ---------------------------------------------------------------------------
// K4: LIF2 + attention score + online softmax + feat accumulation, fully
// fused. One wave (=block) per batch row, lane = h; spk2 never hits memory.
// Chunked 8-deep prefetch as in K2.
// ---------------------------------------------------------------------------
__global__ __launch_bounds__(64) void k4_lif2_attn(
    const float* __restrict__ y2, const float* __restrict__ decay,
    const float* __restrict__ Wa, const float* __restrict__ ba,
    float* __restrict__ feat, unsigned int* __restrict__ cnt)
{
  const int b = blockIdx.x;
  const int lane = threadIdx.x;
  const float d = 1.f / (1.f + expf(-decay[lane]));
  const float wa = Wa[lane];
  const float bav = ba[0];
  const float* p = y2 + (size_t)b * T_ * H2 + lane;
  float v = 0.f, z = 0.f, m = -INFINITY, l = 0.f, f = 0.f;
  unsigned int c = 0;

  float xa[8], xb[8];
  #pragma unroll
  for (int j = 0; j < 8; ++j) xa[j] = p[(size_t)j * H2];

  for (int ch = 0; ch < 125; ++ch) {
    const int tb = ch * 8;
    if (ch + 1 < 125) {
      #pragma unroll
      for (int j = 0; j < 8; ++j) xb[j] = p[(size_t)(tb + 8 + j) * H2];
    }
    #pragma unroll
    for (int j = 0; j < 8; ++j) {
      v = v * d * (1.f - z) + xa[j];
      const bool sp = (v - 0.5f > 0.f);
      z = sp ? 1.f : 0.f;
      c += sp;
      float s = z * wa;
      s += __shfl_xor(s, 1);  s += __shfl_xor(s, 2);  s += __shfl_xor(s, 4);
      s += __shfl_xor(s, 8);  s += __shfl_xor(s, 16); s += __shfl_xor(s, 32);
      s += bav;
      if (s > m) {                       // wave-uniform branch
        const float sc2 = expf(m - s);   // first iter: exp(-inf)=0
        l = l * sc2 + 1.0f;
        f = f * sc2 + z;
        m = s;
      } else {
        const float pe = expf(s - m);
        l += pe;
        f += pe * z;
      }
    }
    #pragma unroll
    for (int j = 0; j < 8; ++j) xa[j] = xb[j];
  }

  feat[(size_t)b * H2 + lane] = f / l;
  c += __shfl_xor(c, 1);  c += __shfl_xor(c, 2);  c += __shfl_xor(c, 4);
  c += __shfl_xor(c, 8);  c += __shfl_xor(c, 16); c += __shfl_xor(c, 32);
  if (lane == 0) atomicAdd(cnt, c);
}

// ---------------------------------------------------------------------------
// K5: logits = feat @ Wo + bo; rate from spike counters
// ---------------------------------------------------------------------------
__global__ __launch_bounds__(256) void k5_logits(
    const float* __restrict__ feat, const float* __restrict__ Wo,
    const float* __restrict__ bo, const unsigned int* __restrict__ cnt,
    float* __restrict__ out)
{
  const int b = threadIdx.x;
  float a0 = bo[0], a1 = bo[1], a2 = bo[2], a3 = bo[3];
  const float* fr = feat + (size_t)b * H2;
  #pragma unroll 8
  for (int h = 0; h < H2; ++h) {
    const float fv = fr[h];
    a0 = fmaf(fv, Wo[h * 4 + 0], a0);
    a1 = fmaf(fv, Wo[h * 4 + 1], a1);
    a2 = fmaf(fv, Wo[h * 4 + 2], a2);
    a3 = fmaf(fv, Wo[h * 4 + 3], a3);
  }
  out[b * 4 + 0] = a0; out[b * 4 + 1] = a1;
  out[b * 4 + 2] = a2; out[b * 4 + 3] = a3;
  if (b == 0) {
    const double r1 = (double)cnt[0] / ((double)MTOT * H1);
    const double r2 = (double)cnt[1] / ((double)MTOT * H2);
    out[1024] = (float)(0.5 * (r1 + r2));
  }
}

extern "C" void kernel_launch(void* const* d_in, const int* in_sizes, int n_in,
                              void* d_out, int out_size, void* d_ws, size_t ws_size,
                              hipStream_t stream) {
  const float* x_seq = (const float*)d_in[0];
  const float* W1    = (const float*)d_in[1];
  const float* b1    = (const float*)d_in[2];
  const float* ln1s  = (const float*)d_in[3];
  const float* ln1b  = (const float*)d_in[4];
  const float* dc1   = (const float*)d_in[5];
  const float* W2    = (const float*)d_in[6];
  const float* b2    = (const float*)d_in[7];
  const float* ln2s  = (const float*)d_in[8];
  const float* ln2b  = (const float*)d_in[9];
  const float* dc2   = (const float*)d_in[10];
  const float* Wa    = (const float*)d_in[11];
  const float* ba    = (const float*)d_in[12];
  const float* Wo    = (const float*)d_in[13];
  const float* bo    = (const float*)d_in[14];
  float* out = (float*)d_out;

  char* ws = (char*)d_ws;
  float* buf1        = (float*)ws;                      // [256000][128] = 131,072,000 B
  float* buf2        = (float*)(ws + 131072000);        // [256000][64] =  65,536,000 B
  unsigned int* cnt  = (unsigned int*)(ws + 196608000); // 2 uints
  float* feat        = (float*)(ws + 196608256);        // [256][64]

  hipMemsetAsync(cnt, 0, 2 * sizeof(unsigned int), stream);
  k1_gemm_gelu_ln<<<MTOT / 128, 256, 0, stream>>>(x_seq, W1, b1, ln1s, ln1b, buf1);
  k2_lif1<<<(B_ * H1) / 64, 64, 0, stream>>>(buf1, dc1, cnt);
  k3_gemm_ln<<<MTOT / 128, 256, 0, stream>>>(buf1, W2, b2, ln2s, ln2b, buf2);
  k4_lif2_attn<<<B_, 64, 0, stream>>>(buf2, dc2, Wa, ba, feat, cnt + 1);
  k5_logits<<<1, 256, 0, stream>>>(feat, Wo, bo, cnt, out);
}

// Round 3
// 804.903 us; speedup vs baseline: 1.3637x; 1.3637x over previous
//
#include <hip/hip_runtime.h>
#include <math.h>

#define B_   256
#define T_   1000
#define F_   310
#define H1   128
#define H2   64
#define MTOT (B_*T_)   // 256000

typedef __attribute__((ext_vector_type(8))) short bf16x8;
typedef __attribute__((ext_vector_type(4))) float f32x4;
typedef __attribute__((ext_vector_type(8))) unsigned short us8;

__device__ __forceinline__ unsigned short f2bf(float x) {
  unsigned int u = __float_as_uint(x);
  unsigned int r = (u + 0x7FFFu + ((u >> 16) & 1u)) >> 16;   // RNE
  return (unsigned short)r;
}
__device__ __forceinline__ float bf2f(unsigned short h) {
  return __uint_as_float((unsigned int)h << 16);
}

__device__ __forceinline__ float gelu_tanh(float x) {
  // tanh(u) = 1 - 2/(1+e^{2u})
  float u = 0.7978845608028654f * (x + 0.044715f * x * x * x);
  float e = __expf(2.f * u);
  float t = 1.f - 2.f / (e + 1.f);
  return 0.5f * x * (1.f + t);
}

// ---------------------------------------------------------------------------
// K0: precompute transposed + hi/lo-split weights.
// Wt1h/Wt1l: [128][320] bf16 (zero-padded K 310->320); Wt2h/l: [64][128].
// ---------------------------------------------------------------------------
__global__ __launch_bounds__(256) void k0_prep(
    const float* __restrict__ W1, const float* __restrict__ W2,
    unsigned short* __restrict__ Wt1h, unsigned short* __restrict__ Wt1l,
    unsigned short* __restrict__ Wt2h, unsigned short* __restrict__ Wt2l)
{
  int gid = blockIdx.x * 256 + threadIdx.x;   // grid = 192 blocks -> gid < 49152
  if (gid < 128 * 320) {
    int n = gid / 320, k = gid % 320;
    float w = (k < F_) ? W1[(size_t)k * H1 + n] : 0.f;
    unsigned short h = f2bf(w);
    Wt1h[n * 320 + k] = h;
    Wt1l[n * 320 + k] = f2bf(w - bf2f(h));
  } else {
    int g = gid - 128 * 320;   // 0..8191
    int n = g >> 7, k = g & 127;
    float w = W2[(size_t)k * H2 + n];
    unsigned short h = f2bf(w);
    Wt2h[n * 128 + k] = h;
    Wt2l[n * 128 + k] = f2bf(w - bf2f(h));
  }
}

// ---------------------------------------------------------------------------
// K1: out = LN(gelu(A @ W1 + b1)), split-bf16 MFMA (3 terms).
// Block tile 256Mx128N, 4 waves (each 64Mx128N), BK=32, 10 k-steps.
// LDS holds fragment-linear chunks: chunk(g,r) of an M/N-16-tile at
// (g*16+r)*16B -> ds_read_b128 at base+lane*16 is conflict-free/linear.
// ---------------------------------------------------------------------------
__global__ __launch_bounds__(256) void k1_mfma(
    const float* __restrict__ A, const unsigned short* __restrict__ Bh,
    const unsigned short* __restrict__ Bl,
    const float* __restrict__ bias, const float* __restrict__ lns,
    const float* __restrict__ lnb, float* __restrict__ out)
{
  __shared__ unsigned short Ah[16 * 512];
  __shared__ unsigned short Al[16 * 512];
  __shared__ unsigned short Bhs[8 * 512];
  __shared__ unsigned short Bls[8 * 512];
  const int tid = threadIdx.x;
  const int wave = tid >> 6, lane = tid & 63;
  const int m0 = blockIdx.x * 256;

  f32x4 acc[4][8];
  #pragma unroll
  for (int mt = 0; mt < 4; ++mt)
    #pragma unroll
    for (int nt = 0; nt < 8; ++nt) acc[mt][nt] = (f32x4){0.f, 0.f, 0.f, 0.f};

  const int arow0 = tid >> 1;        // 0..127 (and +128)
  const int ahalf = tid & 1;         // which 16-k half of the 32-k tile
  const int bn = tid >> 1, bg0 = (tid & 1) * 2;

  for (int kt = 0; kt < 10; ++kt) {
    const int k0 = kt * 32;
    // ---- global loads (A: 2 rows x 16 k fp32; B: 2+2 us8 from L2) ----
    float4 va[8];
    #pragma unroll
    for (int a2 = 0; a2 < 2; ++a2) {
      const float* src = A + (size_t)(m0 + arow0 + a2 * 128) * F_;
      #pragma unroll
      for (int c = 0; c < 4; ++c) {
        const int kk = k0 + ahalf * 16 + c * 4;
        float4 t;
        if (kk + 3 < F_) {
          t = *(const float4*)(src + kk);
        } else {
          t.x = (kk + 0 < F_) ? src[kk + 0] : 0.f;
          t.y = (kk + 1 < F_) ? src[kk + 1] : 0.f;
          t.z = (kk + 2 < F_) ? src[kk + 2] : 0.f;
          t.w = (kk + 3 < F_) ? src[kk + 3] : 0.f;
        }
        va[a2 * 4 + c] = t;
      }
    }
    us8 vbh[2], vbl[2];
    #pragma unroll
    for (int q = 0; q < 2; ++q) {
      vbh[q] = *(const us8*)(Bh + (size_t)bn * 320 + k0 + (bg0 + q) * 8);
      vbl[q] = *(const us8*)(Bl + (size_t)bn * 320 + k0 + (bg0 + q) * 8);
    }
    // ---- convert A to hi/lo bf16 ----
    us8 hi8[4], lo8[4];
    #pragma unroll
    for (int j = 0; j < 4; ++j) {
      us8 hh, ll;
      #pragma unroll
      for (int e = 0; e < 8; ++e) {
        float4 q4 = va[j * 2 + (e >> 2)];
        float x = (e & 3) == 0 ? q4.x : (e & 3) == 1 ? q4.y : (e & 3) == 2 ? q4.z : q4.w;
        unsigned short h = f2bf(x);
        hh[e] = h;
        ll[e] = f2bf(x - bf2f(h));
      }
      hi8[j] = hh; lo8[j] = ll;
    }
    __syncthreads();   // waves done reading previous k-step
    // ---- LDS writes (fragment-linear) ----
    #pragma unroll
    for (int j = 0; j < 4; ++j) {
      const int row = arow0 + (j >> 1) * 128;
      const int g = ahalf * 2 + (j & 1);
      const int idx = (row >> 4) * 512 + (g * 16 + (row & 15)) * 8;
      *(us8*)&Ah[idx] = hi8[j];
      *(us8*)&Al[idx] = lo8[j];
    }
    #pragma unroll
    for (int q = 0; q < 2; ++q) {
      const int idx = (bn >> 4) * 512 + ((bg0 + q) * 16 + (bn & 15)) * 8;
      *(us8*)&Bhs[idx] = vbh[q];
      *(us8*)&Bls[idx] = vbl[q];
    }
    __syncthreads();
    // ---- MFMA ----
    bf16x8 afh[4], afl[4];
    #pragma unroll
    for (int mt = 0; mt < 4; ++mt) {
      const int base = (wave * 4 + mt) * 512 + lane * 8;
      afh[mt] = *(const bf16x8*)&Ah[base];
      afl[mt] = *(const bf16x8*)&Al[base];
    }
    #pragma unroll
    for (int nt = 0; nt < 8; ++nt) {
      const int bbase = nt * 512 + lane * 8;
      bf16x8 bfh = *(const bf16x8*)&Bhs[bbase];
      bf16x8 bfl = *(const bf16x8*)&Bls[bbase];
      #pragma unroll
      for (int mt = 0; mt < 4; ++mt) {
        acc[mt][nt] = __builtin_amdgcn_mfma_f32_16x16x32_bf16(afh[mt], bfh, acc[mt][nt], 0, 0, 0);
        acc[mt][nt] = __builtin_amdgcn_mfma_f32_16x16x32_bf16(afh[mt], bfl, acc[mt][nt], 0, 0, 0);
        acc[mt][nt] = __builtin_amdgcn_mfma_f32_16x16x32_bf16(afl[mt], bfh, acc[mt][nt], 0, 0, 0);
      }
    }
  }

  // ---- epilogue: bias + gelu + LN over 128 cols (all in-wave) ----
  const int col0 = lane & 15, rg = lane >> 4;
  float bb[8], ssv[8], sbv[8];
  #pragma unroll
  for (int nt = 0; nt < 8; ++nt) {
    const int c = nt * 16 + col0;
    bb[nt] = bias[c]; ssv[nt] = lns[c]; sbv[nt] = lnb[c];
  }
  #pragma unroll
  for (int mt = 0; mt < 4; ++mt) {
    #pragma unroll
    for (int j = 0; j < 4; ++j) {
      float g[8]; float sum = 0.f;
      #pragma unroll
      for (int nt = 0; nt < 8; ++nt) { g[nt] = gelu_tanh(acc[mt][nt][j] + bb[nt]); sum += g[nt]; }
      sum += __shfl_xor(sum, 1); sum += __shfl_xor(sum, 2);
      sum += __shfl_xor(sum, 4); sum += __shfl_xor(sum, 8);
      const float mu = sum * (1.0f / 128.0f);
      float vs = 0.f;
      #pragma unroll
      for (int nt = 0; nt < 8; ++nt) { float dd = g[nt] - mu; vs += dd * dd; }
      vs += __shfl_xor(vs, 1); vs += __shfl_xor(vs, 2);
      vs += __shfl_xor(vs, 4); vs += __shfl_xor(vs, 8);
      const float rstd = rsqrtf(vs * (1.0f / 128.0f) + 1e-6f);
      const int row = m0 + wave * 64 + mt * 16 + rg * 4 + j;
      float* dst = out + (size_t)row * H1;
      #pragma unroll
      for (int nt = 0; nt < 8; ++nt)
        dst[nt * 16 + col0] = (g[nt] - mu) * rstd * ssv[nt] + sbv[nt];
    }
  }
}

// ---------------------------------------------------------------------------
// K2: LIF scan 1. Reads LN1 out (fp32), writes spikes as bf16 (exact).
// 25-deep double-buffered prefetch (40 chunks); 512 waves -> ~3 MB in flight.
// ---------------------------------------------------------------------------
__global__ __launch_bounds__(64) void k2_lif1(
    const float* __restrict__ buf, unsigned short* __restrict__ spk,
    const float* __restrict__ decay, unsigned int* __restrict__ cnt)
{
  const int gid = blockIdx.x * 64 + threadIdx.x;
  const int b = gid >> 7, h = gid & 127;
  const float d = 1.f / (1.f + __expf(-decay[h]));
  const float* p = buf + (size_t)b * T_ * H1 + h;
  unsigned short* q = spk + (size_t)b * T_ * H1 + h;
  float v = 0.f, z = 0.f; unsigned int c = 0;

  float xa[25], xb[25];
  #pragma unroll
  for (int j = 0; j < 25; ++j) xa[j] = p[(size_t)j * H1];

  for (int ch = 0; ch < 40; ++ch) {
    const int tb = ch * 25;
    if (ch < 39) {
      #pragma unroll
      for (int j = 0; j < 25; ++j) xb[j] = p[(size_t)(tb + 25 + j) * H1];
    }
    #pragma unroll
    for (int j = 0; j < 25; ++j) {
      v = v * d * (1.f - z) + xa[j];
      const bool sp = v > 0.5f;
      z = sp ? 1.f : 0.f;
      c += sp;
      q[(size_t)(tb + j) * H1] = sp ? (unsigned short)0x3F80 : (unsigned short)0;
    }
    #pragma unroll
    for (int j = 0; j < 25; ++j) xa[j] = xb[j];
  }
  c += __shfl_xor(c, 1);  c += __shfl_xor(c, 2);  c += __shfl_xor(c, 4);
  c += __shfl_xor(c, 8);  c += __shfl_xor(c, 16); c += __shfl_xor(c, 32);
  if (threadIdx.x == 0) atomicAdd(cnt, c);
}

// ---------------------------------------------------------------------------
// K3: x2 = LN(spk1 @ W2 + b2), bf16 MFMA. A (spikes) exact in bf16 -> only
// W2 split (2 terms). Block 256Mx64N, 4 waves (64Mx64N), K=128 (4 k-steps).
// ---------------------------------------------------------------------------
__global__ __launch_bounds__(256) void k3_mfma(
    const unsigned short* __restrict__ Aspk, const unsigned short* __restrict__ Bh,
    const unsigned short* __restrict__ Bl,
    const float* __restrict__ bias, const float* __restrict__ lns,
    const float* __restrict__ lnb, float* __restrict__ out)
{
  __shared__ unsigned short Ah[16 * 512];
  __shared__ unsigned short Bhs[4 * 512];
  __shared__ unsigned short Bls[4 * 512];
  const int tid = threadIdx.x;
  const int wave = tid >> 6, lane = tid & 63;
  const int m0 = blockIdx.x * 256;

  f32x4 acc[4][4];
  #pragma unroll
  for (int mt = 0; mt < 4; ++mt)
    #pragma unroll
    for (int nt = 0; nt < 4; ++nt) acc[mt][nt] = (f32x4){0.f, 0.f, 0.f, 0.f};

  for (int kt = 0; kt < 4; ++kt) {
    const int k0 = kt * 32;
    us8 va[4];
    #pragma unroll
    for (int g = 0; g < 4; ++g)
      va[g] = *(const us8*)(Aspk + (size_t)(m0 + tid) * H1 + k0 + g * 8);
    const int n = tid >> 2, bg = tid & 3;
    us8 vbh = *(const us8*)(Bh + (size_t)n * 128 + k0 + bg * 8);
    us8 vbl = *(const us8*)(Bl + (size_t)n * 128 + k0 + bg * 8);
    __syncthreads();
    #pragma unroll
    for (int g = 0; g < 4; ++g) {
      const int idx = (tid >> 4) * 512 + (g * 16 + (tid & 15)) * 8;
      *(us8*)&Ah[idx] = va[g];
    }
    {
      const int idx = (n >> 4) * 512 + (bg * 16 + (n & 15)) * 8;
      *(us8*)&Bhs[idx] = vbh;
      *(us8*)&Bls[idx] = vbl;
    }
    __syncthreads();
    bf16x8 af[4];
    #pragma unroll
    for (int mt = 0; mt < 4; ++mt)
      af[mt] = *(const bf16x8*)&Ah[(wave * 4 + mt) * 512 + lane * 8];
    #pragma unroll
    for (int nt = 0; nt < 4; ++nt) {
      const int bbase = nt * 512 + lane * 8;
      bf16x8 bfh = *(const bf16x8*)&Bhs[bbase];
      bf16x8 bfl = *(const bf16x8*)&Bls[bbase];
      #pragma unroll
      for (int mt = 0; mt < 4; ++mt) {
        acc[mt][nt] = __builtin_amdgcn_mfma_f32_16x16x32_bf16(af[mt], bfh, acc[mt][nt], 0, 0, 0);
        acc[mt][nt] = __builtin_amdgcn_mfma_f32_16x16x32_bf16(af[mt], bfl, acc[mt][nt], 0, 0, 0);
      }
    }
    __syncthreads();
  }

  const int col0 = lane & 15, rg = lane >> 4;
  float bb[4], ssv[4], sbv[4];
  #pragma unroll
  for (int nt = 0; nt < 4; ++nt) {
    const int c = nt * 16 + col0;
    bb[nt] = bias[c]; ssv[nt] = lns[c]; sbv[nt] = lnb[c];
  }
  #pragma unroll
  for (int mt = 0; mt < 4; ++mt) {
    #pragma unroll
    for (int j = 0; j < 4; ++j) {
      float g[4]; float sum = 0.f;
      #pragma unroll
      for (int nt = 0; nt < 4; ++nt) { g[nt] = acc[mt][nt][j] + bb[nt]; sum += g[nt]; }
      sum += __shfl_xor(sum, 1); sum += __shfl_xor(sum, 2);
      sum += __shfl_xor(sum, 4); sum += __shfl_xor(sum, 8);
      const float mu = sum * (1.0f / 64.0f);
      float vs = 0.f;
      #pragma unroll
      for (int nt = 0; nt < 4; ++nt) { float dd = g[nt] - mu; vs += dd * dd; }
      vs += __shfl_xor(vs, 1); vs += __shfl_xor(vs, 2);
      vs += __shfl_xor(vs, 4); vs += __shfl_xor(vs, 8);
      const float rstd = rsqrtf(vs * (1.0f / 64.0f) + 1e-6f);
      const int row = m0 + wave * 64 + mt * 16 + rg * 4 + j;
      float* dst = out + (size_t)row * H2;
      #pragma unroll
      for (int nt = 0; nt < 4; ++nt)
        dst[nt * 16 + col0] = (g[nt] - mu) * rstd * ssv[nt] + sbv[nt];
    }
  }
}

// ---------------------------------------------------------------------------
// K4: LIF2 + attention, fused. One wave per batch; 25-deep prefetch;
// batched shfl reductions + block-online-softmax (independent exps).
// ---------------------------------------------------------------------------
__global__ __launch_bounds__(64) void k4_lif2_attn(
    const float* __restrict__ y2, const float* __restrict__ decay,
    const float* __restrict__ Wa, const float* __restrict__ ba,
    float* __restrict__ feat, unsigned int* __restrict__ cnt)
{
  const int b = blockIdx.x, lane = threadIdx.x;
  const float d = 1.f / (1.f + __expf(-decay[lane]));
  const float wa = Wa[lane];
  const float bav = ba[0];
  const float* p = y2 + (size_t)b * T_ * H2 + lane;
  float v = 0.f, z = 0.f, m = -INFINITY, l = 0.f, f = 0.f;
  unsigned int c = 0;

  float xa[25], xb[25], zv[25], s[25];
  #pragma unroll
  for (int j = 0; j < 25; ++j) xa[j] = p[(size_t)j * H2];

  for (int ch = 0; ch < 40; ++ch) {
    const int tb = ch * 25;
    if (ch < 39) {
      #pragma unroll
      for (int j = 0; j < 25; ++j) xb[j] = p[(size_t)(tb + 25 + j) * H2];
    }
    #pragma unroll
    for (int j = 0; j < 25; ++j) {
      v = v * d * (1.f - z) + xa[j];
      const bool sp = v > 0.5f;
      z = sp ? 1.f : 0.f;
      zv[j] = z;
      c += sp;
    }
    #pragma unroll
    for (int j = 0; j < 25; ++j) {
      float sv = zv[j] * wa;
      sv += __shfl_xor(sv, 1);  sv += __shfl_xor(sv, 2);  sv += __shfl_xor(sv, 4);
      sv += __shfl_xor(sv, 8);  sv += __shfl_xor(sv, 16); sv += __shfl_xor(sv, 32);
      s[j] = sv + bav;
    }
    float mx = s[0];
    #pragma unroll
    for (int j = 1; j < 25; ++j) mx = fmaxf(mx, s[j]);
    const float mc = fmaxf(m, mx);
    const float scale = __expf(m - mc);   // first chunk: exp(-inf)=0
    float ps = 0.f, fs = 0.f;
    #pragma unroll
    for (int j = 0; j < 25; ++j) {
      const float pj = __expf(s[j] - mc);
      ps += pj;
      fs = fmaf(pj, zv[j], fs);
    }
    l = l * scale + ps;
    f = f * scale + fs;
    m = mc;
    #pragma unroll
    for (int j = 0; j < 25; ++j) xa[j] = xb[j];
  }

  feat[(size_t)b * H2 + lane] = f / l;
  c += __shfl_xor(c, 1);  c += __shfl_xor(c, 2);  c += __shfl_xor(c, 4);
  c += __shfl_xor(c, 8);  c += __shfl_xor(c, 16); c += __shfl_xor(c, 32);
  if (lane == 0) atomicAdd(cnt, c);
}

// ---------------------------------------------------------------------------
// K5: logits = feat @ Wo + bo; rate from spike counters
// ---------------------------------------------------------------------------
__global__ __launch_bounds__(256) void k5_logits(
    const float* __restrict__ feat, const float* __restrict__ Wo,
    const float* __restrict__ bo, const unsigned int* __restrict__ cnt,
    float* __restrict__ out)
{
  const int b = threadIdx.x;
  float a0 = bo[0], a1 = bo[1], a2 = bo[2], a3 = bo[3];
  const float* fr = feat + (size_t)b * H2;
  #pragma unroll 8
  for (int h = 0; h < H2; ++h) {
    const float fv = fr[h];
    a0 = fmaf(fv, Wo[h * 4 + 0], a0);
    a1 = fmaf(fv, Wo[h * 4 + 1], a1);
    a2 = fmaf(fv, Wo[h * 4 + 2], a2);
    a3 = fmaf(fv, Wo[h * 4 + 3], a3);
  }
  out[b * 4 + 0] = a0; out[b * 4 + 1] = a1;
  out[b * 4 + 2] = a2; out[b * 4 + 3] = a3;
  if (b == 0) {
    const double r1 = (double)cnt[0] / ((double)MTOT * H1);
    const double r2 = (double)cnt[1] / ((double)MTOT * H2);
    out[1024] = (float)(0.5 * (r1 + r2));
  }
}

extern "C" void kernel_launch(void* const* d_in, const int* in_sizes, int n_in,
                              void* d_out, int out_size, void* d_ws, size_t ws_size,
                              hipStream_t stream) {
  const float* x_seq = (const float*)d_in[0];
  const float* W1    = (const float*)d_in[1];
  const float* b1    = (const float*)d_in[2];
  const float* ln1s  = (const float*)d_in[3];
  const float* ln1b  = (const float*)d_in[4];
  const float* dc1   = (const float*)d_in[5];
  const float* W2    = (const float*)d_in[6];
  const float* b2    = (const float*)d_in[7];
  const float* ln2s  = (const float*)d_in[8];
  const float* ln2b  = (const float*)d_in[9];
  const float* dc2   = (const float*)d_in[10];
  const float* Wa    = (const float*)d_in[11];
  const float* ba    = (const float*)d_in[12];
  const float* Wo    = (const float*)d_in[13];
  const float* bo    = (const float*)d_in[14];
  float* out = (float*)d_out;

  char* ws = (char*)d_ws;
  // buf1 (LN1 out fp32, 131,072,000 B) -- reused as buf2 (x2 fp32) after K2
  float* buf1 = (float*)ws;
  float* buf2 = (float*)ws;
  unsigned short* spk1  = (unsigned short*)(ws + 131072000);   // 65,536,000 B
  unsigned short* Wt1h  = (unsigned short*)(ws + 196608000);   // 81,920 B
  unsigned short* Wt1l  = (unsigned short*)(ws + 196689920);   // 81,920 B
  unsigned short* Wt2h  = (unsigned short*)(ws + 196771840);   // 16,384 B
  unsigned short* Wt2l  = (unsigned short*)(ws + 196788224);   // 16,384 B
  float* feat           = (float*)(ws + 196804608);            // 65,536 B
  unsigned int* cnt     = (unsigned int*)(ws + 196870144);     // 8 B

  hipMemsetAsync(cnt, 0, 2 * sizeof(unsigned int), stream);
  k0_prep<<<192, 256, 0, stream>>>(W1, W2, Wt1h, Wt1l, Wt2h, Wt2l);
  k1_mfma<<<MTOT / 256, 256, 0, stream>>>(x_seq, Wt1h, Wt1l, b1, ln1s, ln1b, buf1);
  k2_lif1<<<(B_ * H1) / 64, 64, 0, stream>>>(buf1, spk1, dc1, cnt);
  k3_mfma<<<MTOT / 256, 256, 0, stream>>>(spk1, Wt2h, Wt2l, b2, ln2s, ln2b, buf2);
  k4_lif2_attn<<<B_, 64, 0, stream>>>(buf2, dc2, Wa, ba, feat, cnt + 1);
  k5_logits<<<1, 256, 0, stream>>>(feat, Wo, bo, cnt, out);
}